// Round 1
// baseline (122.013 us; speedup 1.0000x reference)
//
#include <hip/hip_runtime.h>

// Problem constants (from reference)
constexpr int B = 16384;
constexpr int S = 4;
constexpr int L = 16;
constexpr int D = 256;           // 256 floats per row = 64 lanes x float4
constexpr int BOS_ID = 98;

// One wave (64 lanes) per output row. Rows = B * (S+1) = 81920.
// Block = 256 threads = 4 waves = 4 consecutive rows (4 KB contiguous store).
__global__ __launch_bounds__(256) void actions_emb_kernel(
    const int*   __restrict__ char_ids,     // (B,S,L)
    const int*   __restrict__ char_len,     // (B,S)
    const int*   __restrict__ action_ids,   // (B,S)
    const int*   __restrict__ slot_type,    // (B,S)
    const float* __restrict__ char_table,   // (58,D)
    const float* __restrict__ action_table, // (99,D)
    float*       __restrict__ out)          // (B,S+1,D)
{
    const int lane = threadIdx.x & 63;
    const int row  = (blockIdx.x << 2) + (threadIdx.x >> 6);   // [0, B*5)
    const int b    = row / 5;
    const int so   = row - b * 5;                              // 0..4

    float4* outv = reinterpret_cast<float4*>(out + (size_t)row * D) + lane;

    if (so == 0) {
        // BOS row: broadcast action_table[BOS_ID]
        *outv = *(reinterpret_cast<const float4*>(action_table + BOS_ID * D) + lane);
        return;
    }

    const int bs = b * S + (so - 1);
    const int t  = slot_type[bs];            // wave-uniform

    float4 r = make_float4(0.f, 0.f, 0.f, 0.f);

    if (t == 1) {
        const int aid = action_ids[bs];
        r = *(reinterpret_cast<const float4*>(action_table + aid * D) + lane);
    } else if (t == 0) {
        const int len = char_len[bs];        // wave-uniform, 1..15
        const int4* idv = reinterpret_cast<const int4*>(char_ids + bs * L);
        int4 v0 = idv[0], v1 = idv[1], v2 = idv[2], v3 = idv[3];
        int ids[L] = { v0.x, v0.y, v0.z, v0.w,
                       v1.x, v1.y, v1.z, v1.w,
                       v2.x, v2.y, v2.z, v2.w,
                       v3.x, v3.y, v3.z, v3.w };
        #pragma unroll
        for (int l = 0; l < L; ++l) {
            if (l < len) {                   // wave-uniform guard
                const float4 e = *(reinterpret_cast<const float4*>(
                                       char_table + ids[l] * D) + lane);
                r.x += e.x; r.y += e.y; r.z += e.z; r.w += e.w;
            }
        }
        const float flen = (float)len;
        r.x /= flen; r.y /= flen; r.z /= flen; r.w /= flen;  // exact f32 div, matches ref
    }
    // t == 2 falls through with zeros.

    *outv = r;
}

extern "C" void kernel_launch(void* const* d_in, const int* in_sizes, int n_in,
                              void* d_out, int out_size, void* d_ws, size_t ws_size,
                              hipStream_t stream) {
    const int*   char_ids     = (const int*)  d_in[0];
    const int*   char_len     = (const int*)  d_in[1];
    const int*   action_ids   = (const int*)  d_in[2];
    const int*   slot_type    = (const int*)  d_in[3];
    const float* char_table   = (const float*)d_in[4];
    const float* action_table = (const float*)d_in[5];
    float*       out          = (float*)      d_out;

    const int rows   = B * (S + 1);          // 81920
    const int blocks = rows / 4;             // 20480 blocks of 256 threads

    actions_emb_kernel<<<blocks, 256, 0, stream>>>(
        char_ids, char_len, action_ids, slot_type, char_table, action_table, out);
}

// Round 2
// 115.457 us; speedup vs baseline: 1.0568x; 1.0568x over previous
//
#include <hip/hip_runtime.h>

// Problem constants (from reference)
constexpr int B = 16384;
constexpr int S = 4;
constexpr int L = 16;
constexpr int D = 256;           // 256 floats per row = 64 lanes x float4
constexpr int BOS_ID = 98;

// One wave (64 lanes) = one batch element b = 5 output rows (5 KB contiguous).
// All control loads for the 4 slots issue in parallel:
//   slot_type/char_len/action_ids as int4 (wave-broadcast),
//   all 64 char ids as ONE coalesced per-lane dword load.
// Char-id broadcast via __shfl(constant lane) -> v_readlane -> scalar gather base.
__global__ __launch_bounds__(256) void actions_emb_wave5(
    const int*   __restrict__ char_ids,     // (B,S,L) = (B,64)
    const int*   __restrict__ char_len,     // (B,S)
    const int*   __restrict__ action_ids,   // (B,S)
    const int*   __restrict__ slot_type,    // (B,S)
    const float* __restrict__ char_table,   // (58,D)
    const float* __restrict__ action_table, // (99,D)
    float*       __restrict__ out)          // (B,S+1,D)
{
    const int lane = threadIdx.x & 63;
    const int b    = (blockIdx.x * blockDim.x + threadIdx.x) >> 6;   // [0,B)

    // ---- issue ALL control loads up front (independent, one round trip) ----
    const int4 st4 = *reinterpret_cast<const int4*>(slot_type  + b * S);
    const int4 cl4 = *reinterpret_cast<const int4*>(char_len   + b * S);
    const int4 ai4 = *reinterpret_cast<const int4*>(action_ids + b * S);
    const int  my_ids = char_ids[b * (S * L) + lane];   // lane l holds id (slot l/16, pos l%16)
    const float4 bos = *(reinterpret_cast<const float4*>(action_table + BOS_ID * D) + lane);

    float4* outv = reinterpret_cast<float4*>(out + (size_t)b * 5 * D) + lane;

    // BOS row (row 0 of this batch element)
    outv[0] = bos;

    #pragma unroll
    for (int s = 0; s < S; ++s) {
        const int t   = (s == 0) ? st4.x : (s == 1) ? st4.y : (s == 2) ? st4.z : st4.w;
        const int len = (s == 0) ? cl4.x : (s == 1) ? cl4.y : (s == 2) ? cl4.z : cl4.w;
        const int aid = (s == 0) ? ai4.x : (s == 1) ? ai4.y : (s == 2) ? ai4.z : ai4.w;

        float4 r = make_float4(0.f, 0.f, 0.f, 0.f);

        if (t == 1) {
            r = *(reinterpret_cast<const float4*>(action_table + aid * D) + lane);
        } else if (t == 0) {
            #pragma unroll
            for (int l = 0; l < L; ++l) {
                if (l < len) {                          // wave-uniform in practice
                    const int id = __shfl(my_ids, s * L + l);   // readlane -> SGPR
                    const float4 e = *(reinterpret_cast<const float4*>(
                                           char_table + id * D) + lane);
                    r.x += e.x; r.y += e.y; r.z += e.z; r.w += e.w;
                }
            }
            const float flen = (float)len;
            r.x /= flen; r.y /= flen; r.z /= flen; r.w /= flen;  // exact div, matches ref
        }
        // t == 2: zeros

        outv[(s + 1) * (D / 4)] = r;    // row s+1 of this batch element
    }
}

extern "C" void kernel_launch(void* const* d_in, const int* in_sizes, int n_in,
                              void* d_out, int out_size, void* d_ws, size_t ws_size,
                              hipStream_t stream) {
    const int*   char_ids     = (const int*)  d_in[0];
    const int*   char_len     = (const int*)  d_in[1];
    const int*   action_ids   = (const int*)  d_in[2];
    const int*   slot_type    = (const int*)  d_in[3];
    const float* char_table   = (const float*)d_in[4];
    const float* action_table = (const float*)d_in[5];
    float*       out          = (float*)      d_out;

    // One wave per batch element: B waves = B*64 threads; 256-thread blocks.
    const int blocks = B / 4;   // 4096 blocks x 4 waves
    actions_emb_wave5<<<blocks, 256, 0, stream>>>(
        char_ids, char_len, action_ids, slot_type, char_table, action_table, out);
}

// Round 4
// 114.763 us; speedup vs baseline: 1.0632x; 1.0060x over previous
//
#include <hip/hip_runtime.h>

// Problem constants (from reference)
constexpr int B = 16384;
constexpr int S = 4;
constexpr int L = 16;
constexpr int D = 256;           // 256 floats per row = 64 lanes x float4
constexpr int BOS_ID = 98;

// Native vector type for nontemporal stores (HIP's float4 class is rejected
// by __builtin_nontemporal_store).
typedef float vfloat4 __attribute__((ext_vector_type(4)));

// One wave (64 lanes) = TWO batch elements = 10 output rows (10 KB stores).
// Control data for both elements issues up front (independent loads);
// char-id broadcast via __shfl(constant lane) -> v_readlane -> scalar base.
// Output stores are nontemporal (out is never re-read).
__device__ __forceinline__ void process_elem(
    int b, int lane, int4 st4, int4 cl4, int4 ai4, int my_ids,
    const float* __restrict__ char_table,
    const float* __restrict__ action_table,
    vfloat4 bos, float* __restrict__ out)
{
    vfloat4* outv = reinterpret_cast<vfloat4*>(out + (size_t)b * 5 * D) + lane;
    __builtin_nontemporal_store(bos, &outv[0]);    // BOS row

    #pragma unroll
    for (int s = 0; s < S; ++s) {
        const int t   = (s == 0) ? st4.x : (s == 1) ? st4.y : (s == 2) ? st4.z : st4.w;
        const int len = (s == 0) ? cl4.x : (s == 1) ? cl4.y : (s == 2) ? cl4.z : cl4.w;
        const int aid = (s == 0) ? ai4.x : (s == 1) ? ai4.y : (s == 2) ? ai4.z : ai4.w;

        vfloat4 r = (vfloat4)(0.f);

        if (t == 1) {
            r = *(reinterpret_cast<const vfloat4*>(action_table + aid * D) + lane);
        } else if (t == 0) {
            #pragma unroll
            for (int l = 0; l < L; ++l) {
                if (l < len) {                          // wave-uniform guard
                    const int id = __shfl(my_ids, s * L + l);   // readlane -> SGPR
                    const vfloat4 e = *(reinterpret_cast<const vfloat4*>(
                                            char_table + id * D) + lane);
                    r += e;
                }
            }
            const float flen = (float)len;
            r /= flen;                                 // exact f32 div, matches ref
        }
        // t == 2: zeros

        __builtin_nontemporal_store(r, &outv[(s + 1) * (D / 4)]);
    }
}

__global__ __launch_bounds__(256) void actions_emb_wave10(
    const int*   __restrict__ char_ids,     // (B,S,L) = (B,64)
    const int*   __restrict__ char_len,     // (B,S)
    const int*   __restrict__ action_ids,   // (B,S)
    const int*   __restrict__ slot_type,    // (B,S)
    const float* __restrict__ char_table,   // (58,D)
    const float* __restrict__ action_table, // (99,D)
    float*       __restrict__ out)          // (B,S+1,D)
{
    const int lane = threadIdx.x & 63;
    const int e    = (blockIdx.x * blockDim.x + threadIdx.x) >> 6;   // [0, B/2)
    const int b0   = e * 2, b1 = b0 + 1;

    // ---- all control loads for BOTH elements, issued together ----
    const int4 st0 = *reinterpret_cast<const int4*>(slot_type  + b0 * S);
    const int4 cl0 = *reinterpret_cast<const int4*>(char_len   + b0 * S);
    const int4 ai0 = *reinterpret_cast<const int4*>(action_ids + b0 * S);
    const int4 st1 = *reinterpret_cast<const int4*>(slot_type  + b1 * S);
    const int4 cl1 = *reinterpret_cast<const int4*>(char_len   + b1 * S);
    const int4 ai1 = *reinterpret_cast<const int4*>(action_ids + b1 * S);
    const int  ids0 = char_ids[b0 * (S * L) + lane];
    const int  ids1 = char_ids[b1 * (S * L) + lane];
    const vfloat4 bos = *(reinterpret_cast<const vfloat4*>(action_table + BOS_ID * D) + lane);

    process_elem(b0, lane, st0, cl0, ai0, ids0, char_table, action_table, bos, out);
    process_elem(b1, lane, st1, cl1, ai1, ids1, char_table, action_table, bos, out);
}

extern "C" void kernel_launch(void* const* d_in, const int* in_sizes, int n_in,
                              void* d_out, int out_size, void* d_ws, size_t ws_size,
                              hipStream_t stream) {
    const int*   char_ids     = (const int*)  d_in[0];
    const int*   char_len     = (const int*)  d_in[1];
    const int*   action_ids   = (const int*)  d_in[2];
    const int*   slot_type    = (const int*)  d_in[3];
    const float* char_table   = (const float*)d_in[4];
    const float* action_table = (const float*)d_in[5];
    float*       out          = (float*)      d_out;

    // One wave per 2 batch elements: B/2 = 8192 waves; 256-thread blocks -> 2048 blocks.
    const int blocks = B / 8;
    actions_emb_wave10<<<blocks, 256, 0, stream>>>(
        char_ids, char_len, action_ids, slot_type, char_table, action_table, out);
}